// Round 3
// baseline (73.473 us; speedup 1.0000x reference)
//
#include <hip/hip_runtime.h>
#include <math.h>

// PeakSense: out[b,p] = sum_i exp(-0.5*(mz[b,i]-mu[p])^2 * exp(-lv[p])) * iv[b,i],
// terms with arg < -10 dropped.
//
// No-LDS revision (resubmit after infra failure, + branchless search).
// Rationale (round-1 post-mortem): the whole-row 32KB LDS stage + barrier
// was the structure itself costing time -- each element is reused by only
// ~4-5 peaks and the 4MB total footprint is L2-resident, so staging is pure
// overhead (Common-mistake #7). Now:
//  - zero LDS, zero barriers: main loop reads masses/inten direct from
//    global (L1/L2-hit), window is ~71 contiguous elements per peak.
//  - both binary searches (lower & upper bound) as FIXED-TRIP bitwise
//    searches (12 uniform iterations for L=4096), interleaved in one loop:
//    two independent dependent-chains overlap via ILP, no loop-exit
//    divergence across lanes, adds are predicated (cndmask) not branched.
//  - 32 peaks/block, SUB=8 lanes per peak, grid 8x128 = 1024 blocks =
//    4 blocks/CU = 16 waves/CU for latency hiding; ~9 terms per lane.
//  - exact per-term threshold test kept -> same accumulation set as ref.

#define BLOCK 256
#define SUB 8
#define PPB (BLOCK / SUB)   // 32 peaks per block
#define THRESH -10.0f

__global__ __launch_bounds__(BLOCK) void peaksense_kernel(
    const float* __restrict__ mu,
    const float* __restrict__ lv,
    const float* __restrict__ masses,
    const float* __restrict__ inten,
    float* __restrict__ out,
    int B, int L, int N)
{
    const int pg = blockIdx.x;   // peak group
    const int b  = blockIdx.y;
    const int t  = threadIdx.x;

    const float* __restrict__ mrow = masses + (size_t)b * L;
    const float* __restrict__ irow = inten  + (size_t)b * L;

    const int  lp     = t >> 3;        // local peak 0..31
    const int  sub    = t & 7;         // eighth-range selector
    const int  p      = pg * PPB + lp;
    const bool active = (p < N);
    const int  pc     = active ? p : (N - 1);   // clamp for safe loads

    const float mu_p = mu[pc];                 // 8 lanes broadcast-share
    const float lvp  = lv[pc];
    const float inv  = __expf(-lvp);           // 1/sigma^2
    const float nh   = -0.5f * inv;
    // arg >= -10  <=>  |d| <= sqrt(20)*sigma; margin covers fp rounding, the
    // exact per-term test below keeps the result bit-for-bit identical.
    const float r    = sqrtf(20.0f / inv) * 1.00001f + 1e-3f;
    const float tlo  = mu_p - r;
    const float thi  = mu_p + r;

    // ---- bitwise binary searches, interleaved for ILP.
    // start = count of elements with m <  tlo  (== lower_bound)
    // end   = count of elements with m <= thi  (== upper_bound)
    // Invariant (sorted row): {i : m[i] < T} is a prefix; the bitwise
    // counter builds its length in binary. 12 fixed steps for L=4096.
    int c0 = 0, c1 = 0;
    const int step0 = L > 0 ? (1 << (31 - __clz(L))) : 0;
    #pragma unroll
    for (int step = step0; step > 0; step >>= 1) {
        const int i0 = c0 + step;
        const int i1 = c1 + step;
        // guarded loads (i<=L always when the condition can pass; clamp idx)
        const bool ok0 = (i0 <= L) && (mrow[i0 - 1] <  tlo);
        const bool ok1 = (i1 <= L) && (mrow[i1 - 1] <= thi);
        if (ok0) c0 = i0;
        if (ok1) c1 = i1;
    }
    const int start = c0;
    const int end   = c1;

    // ---- main loop: ~9 terms per lane, direct global reads (L1/L2-hit) ----
    float acc = 0.0f;
    for (int i = start + sub; i < end; i += SUB) {
        const float m   = mrow[i];
        const float w   = irow[i];
        const float d   = m - mu_p;
        const float arg = d * d * nh;
        if (arg >= THRESH)
            acc += __expf(arg) * w;
    }
    acc += __shfl_xor(acc, 1);                 // merge within the 8-lane group
    acc += __shfl_xor(acc, 2);
    acc += __shfl_xor(acc, 4);
    if (sub == 0 && active)
        out[(size_t)b * N + p] = acc;          // exactly-once '=' write
}

extern "C" void kernel_launch(void* const* d_in, const int* in_sizes, int n_in,
                              void* d_out, int out_size, void* d_ws, size_t ws_size,
                              hipStream_t stream) {
    const float* mu     = (const float*)d_in[0];
    const float* lv     = (const float*)d_in[1];
    const float* masses = (const float*)d_in[2];
    const float* inten  = (const float*)d_in[3];
    float* out = (float*)d_out;

    const int N = in_sizes[0];
    const int B = out_size / N;
    const int L = in_sizes[2] / B;

    const int pgroups = (N + PPB - 1) / PPB;   // 8 for N=256
    dim3 grid(pgroups, B);                     // 1024 blocks -> 4 per CU
    peaksense_kernel<<<grid, BLOCK, 0, stream>>>(mu, lv, masses, inten, out, B, L, N);
}